// Round 1
// baseline (38926.059 us; speedup 1.0000x reference)
//
#include <hip/hip_runtime.h>

#define T_STEPS 512
#define H1N 128
#define H2N 64
#define BB 8

// ws layout (floats):
//   WP1: 65536 floats,  WP1[(j*64+gg)*8+k]  = w_hh1[(gg+64k)*128 + j],  j in [0,128)
//   WP2: 49152 floats,  WP2[(j*64+gg)*4+k2] = j<128 ? w_ih2[(gg+64k2)*128+j]
//                                                   : w_hh2[(gg+64k2)*64 + (j-128)], j in [0,192)
#define WP1_FLOATS 65536
#define WP2_FLOATS 49152

__global__ __launch_bounds__(512) void prep_kernel(
    const float* __restrict__ w_hh1, const float* __restrict__ w_ih2,
    const float* __restrict__ w_hh2, float* __restrict__ ws)
{
  int idx = blockIdx.x * 512 + threadIdx.x;
  if (idx < WP1_FLOATS) {
    int k = idx & 7; int t2 = idx >> 3; int gg = t2 & 63; int j = t2 >> 6;
    ws[idx] = w_hh1[(gg + 64 * k) * H1N + j];
  }
  int idx2 = idx - WP1_FLOATS;
  if (idx2 >= 0 && idx2 < WP2_FLOATS) {
    int k2 = idx2 & 3; int t2 = idx2 >> 2; int gg = t2 & 63; int j = t2 >> 6;
    int g2 = gg + 64 * k2;
    ws[WP1_FLOATS + idx2] = (j < 128) ? w_ih2[g2 * H1N + j]
                                      : w_hh2[g2 * H2N + (j - 128)];
  }
}

__device__ __forceinline__ float rcpf_(float x) { return __builtin_amdgcn_rcpf(x); }
__device__ __forceinline__ float sigf(float x) { return rcpf_(1.0f + __expf(-x)); }
// tanh(x) = 1 - 2/(exp(2x)+1); saturates correctly at +/-inf
__device__ __forceinline__ float tanhf_(float x) { return 1.0f - 2.0f * rcpf_(__expf(2.0f * x) + 1.0f); }

__global__ __launch_bounds__(512, 2) void lstm_fused_kernel(
    const float* __restrict__ x,
    const float* __restrict__ w_ih1, const float* __restrict__ b_ih1, const float* __restrict__ b_hh1,
    const float* __restrict__ b_ih2, const float* __restrict__ b_hh2,
    const float* __restrict__ w_d1, const float* __restrict__ b_d1,
    const float* __restrict__ w_d2, const float* __restrict__ b_d2,
    const float* __restrict__ ws, float* __restrict__ out)
{
  __shared__ float h1s[2][BB][H1N + 4];   // +4 pad: rows land on distinct bank groups
  __shared__ float h2s[2][BB][H2N + 4];
  __shared__ float dh[BB][25];

  const int tid = threadIdx.x;
  const int b  = tid & 7;
  const int gg = tid >> 3;            // [0,64)
  const int r0 = blockIdx.x * BB;

  const float4* __restrict__ wp1 = (const float4*)ws;                 // f4 idx: (j*64+gg)*2 + {0,1}
  const float4* __restrict__ wp2 = (const float4*)(ws + WP1_FLOATS);  // f4 idx: (j*64+gg)

  // Per-thread persistent params: gates g = gg + 64k (k=0..7): i,i,f,f,g,g,o,o for units gg, gg+64
  float wih[8], bi1[8], bi2[4];
  #pragma unroll
  for (int k = 0; k < 8; ++k) { int g = gg + 64 * k; wih[k] = w_ih1[g]; bi1[k] = b_ih1[g] + b_hh1[g]; }
  #pragma unroll
  for (int k = 0; k < 4; ++k) { int g2 = gg + 64 * k; bi2[k] = b_ih2[g2] + b_hh2[g2]; }

  h1s[0][b][gg] = 0.f; h1s[0][b][gg + 64] = 0.f;
  h2s[0][b][gg] = 0.f;
  float c1a = 0.f, c1b = 0.f, c2 = 0.f;
  __syncthreads();

  const float* __restrict__ xr = x + (r0 + b) * T_STEPS;

  for (int t = 0; t < T_STEPS; ++t) {
    const int cur = t & 1, nxt = cur ^ 1;
    const float xt = xr[t];

    // ---- Phase A: layer-1 gates for row b, units gg & gg+64 ----
    float a0 = fmaf(xt, wih[0], bi1[0]);
    float a1 = fmaf(xt, wih[1], bi1[1]);
    float a2 = fmaf(xt, wih[2], bi1[2]);
    float a3 = fmaf(xt, wih[3], bi1[3]);
    float a4 = fmaf(xt, wih[4], bi1[4]);
    float a5 = fmaf(xt, wih[5], bi1[5]);
    float a6 = fmaf(xt, wih[6], bi1[6]);
    float a7 = fmaf(xt, wih[7], bi1[7]);

    const float* __restrict__ h1c = &h1s[cur][b][0];
#define STEP_A(HV, JJ) { \
      const float4 wA = wp1[((j + (JJ)) * 64 + gg) * 2];     \
      const float4 wB = wp1[((j + (JJ)) * 64 + gg) * 2 + 1]; \
      a0 = fmaf(wA.x, (HV), a0); a1 = fmaf(wA.y, (HV), a1);  \
      a2 = fmaf(wA.z, (HV), a2); a3 = fmaf(wA.w, (HV), a3);  \
      a4 = fmaf(wB.x, (HV), a4); a5 = fmaf(wB.y, (HV), a5);  \
      a6 = fmaf(wB.z, (HV), a6); a7 = fmaf(wB.w, (HV), a7); }
    for (int j = 0; j < H1N; j += 4) {
      const float4 h4 = *(const float4*)(h1c + j);
      STEP_A(h4.x, 0) STEP_A(h4.y, 1) STEP_A(h4.z, 2) STEP_A(h4.w, 3)
    }
#undef STEP_A

    // activations + c/h update (i=a0/a1, f=a2/a3, g=a4/a5, o=a6/a7)
    const float i0 = sigf(a0), i1 = sigf(a1);
    const float f0 = sigf(a2), f1 = sigf(a3);
    const float g0 = tanhf_(a4), g1 = tanhf_(a5);
    const float o0 = sigf(a6), o1 = sigf(a7);
    c1a = fmaf(f0, c1a, i0 * g0);
    c1b = fmaf(f1, c1b, i1 * g1);
    const float h1a = o0 * tanhf_(c1a);
    const float h1b = o1 * tanhf_(c1b);
    h1s[nxt][b][gg]      = h1a;   // safe: this step only reads h1s[cur]
    h1s[nxt][b][gg + 64] = h1b;
    __syncthreads();   // S1: new h1 visible

    // ---- Phase B: layer-2 gates for row b, unit gg (i,f,g,o = k2 0..3) ----
    float p0 = bi2[0], p1 = bi2[1], p2 = bi2[2], p3 = bi2[3];
    const float* __restrict__ h1n = &h1s[nxt][b][0];
#define STEP_B(HV, JIDX) { \
      const float4 w = wp2[(JIDX) * 64 + gg];               \
      p0 = fmaf(w.x, (HV), p0); p1 = fmaf(w.y, (HV), p1);   \
      p2 = fmaf(w.z, (HV), p2); p3 = fmaf(w.w, (HV), p3); }
    for (int j = 0; j < H1N; j += 4) {
      const float4 h4 = *(const float4*)(h1n + j);
      STEP_B(h4.x, j) STEP_B(h4.y, j + 1) STEP_B(h4.z, j + 2) STEP_B(h4.w, j + 3)
    }
    const float* __restrict__ h2c = &h2s[cur][b][0];
    for (int j = 0; j < H2N; j += 4) {
      const float4 h4 = *(const float4*)(h2c + j);
      STEP_B(h4.x, 128 + j) STEP_B(h4.y, 128 + j + 1) STEP_B(h4.z, 128 + j + 2) STEP_B(h4.w, 128 + j + 3)
    }
#undef STEP_B
    const float i2 = sigf(p0), f2 = sigf(p1);
    const float g2v = tanhf_(p2), o2 = sigf(p3);
    c2 = fmaf(f2, c2, i2 * g2v);
    h2s[nxt][b][gg] = o2 * tanhf_(c2);
    __syncthreads();   // S2: new h2 visible / old buffers reusable
  }

  // ---- Dense head: final h2 is in h2s[0] (T even) ----
  if (gg < 25) {
    float acc = b_d1[gg];
    const float* __restrict__ hf = &h2s[0][b][0];
    #pragma unroll
    for (int u = 0; u < H2N; ++u) acc = fmaf(hf[u], w_d1[gg * H2N + u], acc);
    dh[b][gg] = acc;
  }
  __syncthreads();
  if (tid < BB) {
    float yv = b_d2[0];
    #pragma unroll
    for (int d = 0; d < 25; ++d) yv = fmaf(dh[tid][d], w_d2[d], yv);
    out[r0 + tid] = yv;
  }
}

extern "C" void kernel_launch(void* const* d_in, const int* in_sizes, int n_in,
                              void* d_out, int out_size, void* d_ws, size_t ws_size,
                              hipStream_t stream) {
  const float* x     = (const float*)d_in[0];
  const float* w_ih1 = (const float*)d_in[1];
  const float* w_hh1 = (const float*)d_in[2];
  const float* b_ih1 = (const float*)d_in[3];
  const float* b_hh1 = (const float*)d_in[4];
  const float* w_ih2 = (const float*)d_in[5];
  const float* w_hh2 = (const float*)d_in[6];
  const float* b_ih2 = (const float*)d_in[7];
  const float* b_hh2 = (const float*)d_in[8];
  const float* w_d1  = (const float*)d_in[9];
  const float* b_d1  = (const float*)d_in[10];
  const float* w_d2  = (const float*)d_in[11];
  const float* b_d2  = (const float*)d_in[12];
  float* ws  = (float*)d_ws;
  float* out = (float*)d_out;

  // Repack weights for coalesced per-step streaming (deterministic, every call)
  prep_kernel<<<(WP1_FLOATS + WP2_FLOATS) / 512, 512, 0, stream>>>(w_hh1, w_ih2, w_hh2, ws);

  // 256 blocks x 512 threads: block owns 8 batch rows, persistent over all 512 steps
  lstm_fused_kernel<<<2048 / BB, 512, 0, stream>>>(
      x, w_ih1, b_ih1, b_hh1, b_ih2, b_hh2, w_d1, b_d1, w_d2, b_d2, ws, out);
}

// Round 2
// 4325.395 us; speedup vs baseline: 8.9994x; 8.9994x over previous
//
#include <hip/hip_runtime.h>

#define TS 512
#define NT 512

// ws float layout:
//  [0       , 96*512 )  rws1[i][tid]   i=p*24+q (q<24): w_hh1[(u1+128p)][jc1*32+q], u1=tid>>2, jc1=tid&3
//  [96*512  , 160*512)  rws2[i][tid]   i=p*16+q (q<16): w2cat[(u2+64p)][jc2*24+q], u2=tid>>3, jc2=tid&7
//  [160*512 , 224*512)  lwsg[k][tid]   k<32: L1 spill (p=k>>3, q=24+(k&7)); k>=32: L2 spill (p=(k-32)>>3, q=16+((k-32)&7))
//  [224*512 , +512   )  bs1[g] = b_ih1+b_hh1
//  [224*512+512, +256 )  bs2[g] = b_ih2+b_hh2
#define WS_BS1 (224*512)

__global__ __launch_bounds__(512) void prep(
    const float* __restrict__ w_hh1, const float* __restrict__ w_ih2,
    const float* __restrict__ w_hh2,
    const float* __restrict__ b_ih1, const float* __restrict__ b_hh1,
    const float* __restrict__ b_ih2, const float* __restrict__ b_hh2,
    float* __restrict__ ws)
{
  int idx = blockIdx.x * 512 + threadIdx.x;
  if (idx < 96*512) {
    int i = idx >> 9, tid = idx & 511;
    int p = i / 24, q = i % 24;
    int u1 = tid >> 2, jc1 = tid & 3;
    ws[idx] = w_hh1[(u1 + 128*p)*128 + jc1*32 + q];
  } else if (idx < 160*512) {
    int i = (idx >> 9) - 96, tid = idx & 511;
    int p = i >> 4, q = i & 15;
    int u2 = tid >> 3, jc2 = tid & 7;
    int col = jc2*24 + q, g = u2 + 64*p;
    ws[idx] = (col < 128) ? w_ih2[g*128 + col] : w_hh2[g*64 + col - 128];
  } else if (idx < 224*512) {
    int k = (idx >> 9) - 160, tid = idx & 511;
    if (k < 32) {
      int p = k >> 3, q = 24 + (k & 7);
      int u1 = tid >> 2, jc1 = tid & 3;
      ws[idx] = w_hh1[(u1 + 128*p)*128 + jc1*32 + q];
    } else {
      int kk = k - 32; int p = kk >> 3, q = 16 + (kk & 7);
      int u2 = tid >> 3, jc2 = tid & 7;
      int col = jc2*24 + q, g = u2 + 64*p;
      ws[idx] = (col < 128) ? w_ih2[g*128 + col] : w_hh2[g*64 + col - 128];
    }
  } else if (idx < 224*512 + 768) {
    int b = idx - 224*512;
    ws[idx] = (b < 512) ? (b_ih1[b] + b_hh1[b]) : (b_ih2[b-512] + b_hh2[b-512]);
  }
}

__device__ __forceinline__ float rcpf_(float x) { return __builtin_amdgcn_rcpf(x); }
__device__ __forceinline__ float sigf(float x) { return rcpf_(1.0f + __expf(-x)); }
__device__ __forceinline__ float tanhf_(float x) { return 1.0f - 2.0f * rcpf_(__expf(2.0f * x) + 1.0f); }

__global__ __launch_bounds__(512, 2) void lstm_fused(
    const float* __restrict__ x, const float* __restrict__ w_ih1,
    const float* __restrict__ w_d1, const float* __restrict__ b_d1,
    const float* __restrict__ w_d2, const float* __restrict__ b_d2,
    const float* __restrict__ ws, float* __restrict__ out)
{
  __shared__ __align__(16) float lds_w[64*512];   // 128 KB weight spill [k][tid]
  __shared__ __align__(16) float x_lds[8*512];    // 16 KB
  __shared__ __align__(16) float hcat[2][8][196]; // 12.25 KB: row = [h1(128) | h2(64) | pad]

  const int tid = threadIdx.x;
  const int u1 = tid >> 2, jc1 = tid & 3;   // layer1: unit u1, j-chunk jc1*32
  const int u2 = tid >> 3, jc2 = tid & 7;   // layer2: unit u2, j-chunk jc2*24
  const int r0 = blockIdx.x * 8;

  // ---- startup: weights -> regs/LDS (coalesced), x -> LDS, zero h ----
  float w1r[96];
  #pragma unroll
  for (int i = 0; i < 96; ++i) w1r[i] = ws[i*512 + tid];
  float w2r[64];
  #pragma unroll
  for (int i = 0; i < 64; ++i) w2r[i] = ws[(96+i)*512 + tid];
  #pragma unroll
  for (int k = 0; k < 64; ++k) lds_w[k*512 + tid] = ws[(160+k)*512 + tid];
  #pragma unroll
  for (int i = 0; i < 8; ++i) x_lds[i*512 + tid] = x[(r0 + i)*512 + tid];
  for (int i = tid; i < 2*8*196; i += 512) (&hcat[0][0][0])[i] = 0.f;

  const float* bs1 = ws + WS_BS1;
  const float* bs2 = bs1 + 512;
  float bb[4], wx[4], b2[4];
  #pragma unroll
  for (int p = 0; p < 4; ++p) {
    bb[p] = bs1[u1 + 128*p];
    wx[p] = w_ih1[u1 + 128*p];
    b2[p] = bs2[u2 + 64*p];
  }
  float c1[4] = {0.f,0.f,0.f,0.f}, c2[4] = {0.f,0.f,0.f,0.f};
  __syncthreads();

  for (int t = 0; t < TS; ++t) {
    float* hA = &hcat[t & 1][0][0];         // read h1[t-1]; B writes h2[t] here
    float* hB = &hcat[(t & 1) ^ 1][0][0];   // A writes h1[t]; holds h2[t-1]

    // ================= Phase A: layer 1 =================
    float w1l[32];
    #pragma unroll
    for (int k = 0; k < 32; ++k) w1l[k] = lds_w[k*512 + tid];

    #pragma unroll
    for (int b = 0; b < 4; ++b) {
      float pa[4][2];
      #pragma unroll
      for (int p = 0; p < 4; ++p) { pa[p][0] = 0.f; pa[p][1] = 0.f; }
      #pragma unroll
      for (int k = 0; k < 2; ++k) {
        const float* hp = hA + (2*b + k)*196 + jc1*32;
#define FMA1(Q, HV) { _Pragma("unroll") for (int p = 0; p < 4; ++p) { \
          const float wv = ((Q) < 24) ? w1r[p*24 + (Q)] : w1l[p*8 + ((Q) - 24)]; \
          pa[p][k] = fmaf(wv, (HV), pa[p][k]); } }
        #pragma unroll
        for (int q4 = 0; q4 < 8; ++q4) {
          const float4 h4 = *(const float4*)(hp + q4*4);
          FMA1(q4*4+0, h4.x) FMA1(q4*4+1, h4.y) FMA1(q4*4+2, h4.z) FMA1(q4*4+3, h4.w)
        }
#undef FMA1
      }
      // reduce-scatter over 4 jc1 lanes -> lane jc1&1 owns row 2b+(jc1&1)
      float red[4];
      #pragma unroll
      for (int p = 0; p < 4; ++p) {
        float v0 = pa[p][0] + __shfl_xor(pa[p][0], 2, 64);
        float v1 = pa[p][1] + __shfl_xor(pa[p][1], 2, 64);
        const float send = (jc1 & 1) ? v0 : v1;
        const float keep = (jc1 & 1) ? v1 : v0;
        red[p] = keep + __shfl_xor(send, 1, 64);
      }
      const int r = 2*b + (jc1 & 1);
      const float xt = x_lds[r*512 + t];
      const float gi = sigf (red[0] + bb[0] + xt*wx[0]);
      const float gf = sigf (red[1] + bb[1] + xt*wx[1]);
      const float gg = tanhf_(red[2] + bb[2] + xt*wx[2]);
      const float go = sigf (red[3] + bb[3] + xt*wx[3]);
      c1[b] = fmaf(gf, c1[b], gi*gg);
      const float h1v = go * tanhf_(c1[b]);
      if (jc1 < 2) hB[r*196 + u1] = h1v;
    }
    __syncthreads();

    // ================= Phase B: layer 2 =================
    float w2l[32];
    #pragma unroll
    for (int k = 0; k < 32; ++k) w2l[k] = lds_w[(32+k)*512 + tid];

    #pragma unroll
    for (int b = 0; b < 4; ++b) {
      float pb[4][2];
      #pragma unroll
      for (int p = 0; p < 4; ++p) { pb[p][0] = 0.f; pb[p][1] = 0.f; }
      #pragma unroll
      for (int k = 0; k < 2; ++k) {
        const float* hp = hB + (2*b + k)*196 + jc2*24;
#define FMA2(Q, HV) { _Pragma("unroll") for (int p = 0; p < 4; ++p) { \
          const float wv = ((Q) < 16) ? w2r[p*16 + (Q)] : w2l[p*8 + ((Q) - 16)]; \
          pb[p][k] = fmaf(wv, (HV), pb[p][k]); } }
        #pragma unroll
        for (int q4 = 0; q4 < 6; ++q4) {
          const float4 h4 = *(const float4*)(hp + q4*4);
          FMA2(q4*4+0, h4.x) FMA2(q4*4+1, h4.y) FMA2(q4*4+2, h4.z) FMA2(q4*4+3, h4.w)
        }
#undef FMA2
      }
      // reduce-scatter over 8 jc2 lanes -> lane jc2&1 owns row 2b+(jc2&1)
      float red[4];
      #pragma unroll
      for (int p = 0; p < 4; ++p) {
        float v0 = pb[p][0];
        v0 += __shfl_xor(v0, 4, 64); v0 += __shfl_xor(v0, 2, 64);
        float v1 = pb[p][1];
        v1 += __shfl_xor(v1, 4, 64); v1 += __shfl_xor(v1, 2, 64);
        const float send = (jc2 & 1) ? v0 : v1;
        const float keep = (jc2 & 1) ? v1 : v0;
        red[p] = keep + __shfl_xor(send, 1, 64);
      }
      const int r = 2*b + (jc2 & 1);
      const float gi = sigf (red[0] + b2[0]);
      const float gf = sigf (red[1] + b2[1]);
      const float gg = tanhf_(red[2] + b2[2]);
      const float go = sigf (red[3] + b2[3]);
      c2[b] = fmaf(gf, c2[b], gi*gg);
      const float h2v = go * tanhf_(c2[b]);
      if (jc2 < 2) hA[r*196 + 128 + u2] = h2v;
    }
    __syncthreads();
  }

  // ---- dense head: final h2 sits in hcat[1][r][128..192) ----
  float* dh = x_lds;  // reuse
  if (tid < 200) {
    const int r = tid / 25, d = tid - r*25;
    float acc = b_d1[d];
    #pragma unroll
    for (int u = 0; u < 64; ++u) acc = fmaf(hcat[1][r][128 + u], w_d1[d*64 + u], acc);
    dh[r*25 + d] = acc;
  }
  __syncthreads();
  if (tid < 8) {
    float y = b_d2[0];
    #pragma unroll
    for (int d = 0; d < 25; ++d) y = fmaf(dh[tid*25 + d], w_d2[d], y);
    out[r0 + tid] = y;
  }
}

extern "C" void kernel_launch(void* const* d_in, const int* in_sizes, int n_in,
                              void* d_out, int out_size, void* d_ws, size_t ws_size,
                              hipStream_t stream) {
  const float* x     = (const float*)d_in[0];
  const float* w_ih1 = (const float*)d_in[1];
  const float* w_hh1 = (const float*)d_in[2];
  const float* b_ih1 = (const float*)d_in[3];
  const float* b_hh1 = (const float*)d_in[4];
  const float* w_ih2 = (const float*)d_in[5];
  const float* w_hh2 = (const float*)d_in[6];
  const float* b_ih2 = (const float*)d_in[7];
  const float* b_hh2 = (const float*)d_in[8];
  const float* w_d1  = (const float*)d_in[9];
  const float* b_d1  = (const float*)d_in[10];
  const float* w_d2  = (const float*)d_in[11];
  const float* b_d2  = (const float*)d_in[12];
  float* ws  = (float*)d_ws;
  float* out = (float*)d_out;

  prep<<<226, 512, 0, stream>>>(w_hh1, w_ih2, w_hh2, b_ih1, b_hh1, b_ih2, b_hh2, ws);
  lstm_fused<<<256, 512, 0, stream>>>(x, w_ih1, w_d1, b_d1, w_d2, b_d2, ws, out);
}

// Round 3
// 934.961 us; speedup vs baseline: 41.6339x; 4.6263x over previous
//
#include <hip/hip_runtime.h>

#define TS 512

typedef _Float16 f16x8 __attribute__((ext_vector_type(8)));
typedef float f32x4 __attribute__((ext_vector_type(4)));

#define MFMA16(a, b, c) __builtin_amdgcn_mfma_f32_16x16x32_f16((a), (b), (c), 0, 0, 0)

// ws (f16) layout:
//  Region A (L1 B-frags): idx = ((w*16 + g*4 + kt)*64 + l)*8 + j, value = W1[n][k]
//      n = g*128 + w*16 + (l&15), k = kt*32 + (l>>4)*8 + j        (65536 f16)
//  Region B (L2 B-frags): idx = 65536 + ((w*24 + g*6 + kt)*64 + l)*8 + j
//      n = g*64 + (w&3)*16 + (l&15), k = kt*32 + (l>>4)*8 + j, W2cat = [w_ih2 | w_hh2]
__global__ __launch_bounds__(512) void prep(
    const float* __restrict__ w_hh1, const float* __restrict__ w_ih2,
    const float* __restrict__ w_hh2, _Float16* __restrict__ wsh)
{
  int idx = blockIdx.x * 512 + threadIdx.x;   // 163840 total
  int slot = idx >> 3, j = idx & 7;
  if (slot < 8192) {
    int w = slot >> 10, f = (slot >> 6) & 15, l = slot & 63;
    int g = f >> 2, kt = f & 3;
    int n = g * 128 + w * 16 + (l & 15);
    int k = kt * 32 + (l >> 4) * 8 + j;
    wsh[idx] = (_Float16)w_hh1[n * 128 + k];
  } else {
    int s2 = slot - 8192;
    int w = s2 / 1536, rem = s2 % 1536, f = rem >> 6, l = rem & 63;
    int g = f / 6, kt = f % 6;
    int n = g * 64 + (w & 3) * 16 + (l & 15);
    int k = kt * 32 + (l >> 4) * 8 + j;
    wsh[idx] = (_Float16)((k < 128) ? w_ih2[n * 128 + k] : w_hh2[n * 64 + (k - 128)]);
  }
}

__device__ __forceinline__ float rcpf_(float x) { return __builtin_amdgcn_rcpf(x); }
__device__ __forceinline__ float sigf(float x) { return rcpf_(1.0f + __expf(-x)); }
__device__ __forceinline__ float tanhf_(float x) { return 1.0f - 2.0f * rcpf_(__expf(2.0f * x) + 1.0f); }

// HC plane: [16 rows][192 f16] per plane, row stride 384 B.
// Element (r, k) lives at byte r*384 + ((kt ^ (r&1))<<6) + (k&31)*2, kt = k>>5  (XOR bank swizzle)
__global__ __launch_bounds__(512, 2) void lstm_mfma(
    const float* __restrict__ x,
    const float* __restrict__ w_ih1,
    const float* __restrict__ b_ih1, const float* __restrict__ b_hh1,
    const float* __restrict__ b_ih2, const float* __restrict__ b_hh2,
    const float* __restrict__ w_d1, const float* __restrict__ b_d1,
    const float* __restrict__ w_d2, const float* __restrict__ b_d2,
    const _Float16* __restrict__ wsh,
    float* __restrict__ out)
{
  __shared__ __align__(16) _Float16 HC[2][16 * 192];   // 12 KB, rows 8..15 stay zero
  __shared__ __align__(16) float x_lds[8 * 516];        // 16.5 KB
  __shared__ float h2f[8][65];
  __shared__ float dh[200];

  const int tid = threadIdx.x;
  const int w   = tid >> 6;      // wave 0..7
  const int l   = tid & 63;
  const int col = l & 15;        // A row / B col / D col
  const int q   = l >> 4;        // k-group / D row-group
  const int r0  = blockIdx.x * 8;

  // ---- persistent B-fragments (weights) in registers ----
  f16x8 B1[4][4];
  #pragma unroll
  for (int g = 0; g < 4; ++g)
    #pragma unroll
    for (int kt = 0; kt < 4; ++kt)
      B1[g][kt] = *(const f16x8*)(wsh + ((w * 16 + g * 4 + kt) * 64 + l) * 8);
  f16x8 B2[4][6];
  #pragma unroll
  for (int g = 0; g < 4; ++g)
    #pragma unroll
    for (int kt = 0; kt < 6; ++kt)
      B2[g][kt] = *(const f16x8*)(wsh + 65536 + ((w * 24 + g * 6 + kt) * 64 + l) * 8);

  // ---- per-lane scalar params ----
  const int u  = w * 16 + col;          // L1 unit
  const int u2 = (w & 3) * 16 + col;    // L2 unit
  float bi1[4], wx1[4], bi2[4];
  #pragma unroll
  for (int g = 0; g < 4; ++g) {
    bi1[g] = b_ih1[g * 128 + u] + b_hh1[g * 128 + u];
    wx1[g] = w_ih1[g * 128 + u];
    bi2[g] = b_ih2[g * 64 + u2] + b_hh2[g * 64 + u2];
  }

  // ---- x -> LDS (stride 516 words), zero h planes ----
  {
    int r = tid >> 6, c = (tid & 63) * 8;
    const float4* src = (const float4*)(x + (r0 + r) * 512 + c);
    float4 v0 = src[0], v1 = src[1];
    *(float4*)(x_lds + r * 516 + c)     = v0;
    *(float4*)(x_lds + r * 516 + c + 4) = v1;
  }
  for (int i = tid; i < 3072; i += 512) ((unsigned*)HC)[i] = 0u;

  // ---- address precompute ----
  const int cp6    = (col & 1) << 6;
  const int abase  = col * 384 + q * 16;            // A-frag read base
  const int su     = (u >> 5) << 6;
  const int h1base = 4 * q * 384 + (u & 31) * 2;
  const int regbase = (w < 4) ? 0 : 2;              // L2 row split across wave pairs
  const int sk     = (4 + (u2 >> 5)) << 6;
  const int h2base = (4 * q + regbase) * 384 + (u2 & 31) * 2;

  float c1[4] = {0.f, 0.f, 0.f, 0.f};
  float c2[2] = {0.f, 0.f};
  char* const hcb = (char*)HC;

  __syncthreads();

  #pragma unroll 1
  for (int t = 0; t < TS; ++t) {
    char* pW = hcb + ((t & 1) ? 6144 : 0);        // h1[t] / h2[t] plane
    char* pR = hcb + ((t & 1) ? 0 : 6144);        // h1[t-1] / h2[t-1] plane

    // ================= Phase A: layer 1 =================
    f16x8 a0 = *(const f16x8*)(pR + (abase + (cp6 ^ (0 << 6))));
    f16x8 a1 = *(const f16x8*)(pR + (abase + (cp6 ^ (1 << 6))));
    f16x8 a2 = *(const f16x8*)(pR + (abase + (cp6 ^ (2 << 6))));
    f16x8 a3 = *(const f16x8*)(pR + (abase + (cp6 ^ (3 << 6))));
    f32x4 accL1[4];
    #pragma unroll
    for (int g = 0; g < 4; ++g) {
      accL1[g] = (f32x4){0.f, 0.f, 0.f, 0.f};
      accL1[g] = MFMA16(a0, B1[g][0], accL1[g]);
      accL1[g] = MFMA16(a1, B1[g][1], accL1[g]);
      accL1[g] = MFMA16(a2, B1[g][2], accL1[g]);
      accL1[g] = MFMA16(a3, B1[g][3], accL1[g]);
    }
    #pragma unroll
    for (int reg = 0; reg < 4; ++reg) {
      const int rr = (q < 2) ? (4 * q + reg) : reg;     // clamp for dead lanes
      const float xv = x_lds[rr * 516 + t];
      float s0 = fmaf(xv, wx1[0], accL1[0][reg] + bi1[0]);
      float s1 = fmaf(xv, wx1[1], accL1[1][reg] + bi1[1]);
      float s2 = fmaf(xv, wx1[2], accL1[2][reg] + bi1[2]);
      float s3 = fmaf(xv, wx1[3], accL1[3][reg] + bi1[3]);
      float ii = sigf(s0), ff = sigf(s1), gg = tanhf_(s2), oo = sigf(s3);
      c1[reg] = fmaf(ff, c1[reg], ii * gg);
      float hv = oo * tanhf_(c1[reg]);
      if (q < 2)
        *(_Float16*)(pW + (h1base + reg * 384 + (su ^ ((reg & 1) << 6)))) = (_Float16)hv;
    }
    __syncthreads();   // the only barrier per step

    // ================= Phase B: layer 2 (K = [h1(t) | h2(t-1)]) =================
    f16x8 e0 = *(const f16x8*)(pW + (abase + (cp6 ^ (0 << 6))));
    f16x8 e1 = *(const f16x8*)(pW + (abase + (cp6 ^ (1 << 6))));
    f16x8 e2 = *(const f16x8*)(pW + (abase + (cp6 ^ (2 << 6))));
    f16x8 e3 = *(const f16x8*)(pW + (abase + (cp6 ^ (3 << 6))));
    f16x8 e4 = *(const f16x8*)(pR + (abase + (cp6 ^ (4 << 6))));
    f16x8 e5 = *(const f16x8*)(pR + (abase + (cp6 ^ (5 << 6))));
    f32x4 accL2[4];
    #pragma unroll
    for (int g = 0; g < 4; ++g) {
      accL2[g] = (f32x4){0.f, 0.f, 0.f, 0.f};
      accL2[g] = MFMA16(e0, B2[g][0], accL2[g]);
      accL2[g] = MFMA16(e1, B2[g][1], accL2[g]);
      accL2[g] = MFMA16(e2, B2[g][2], accL2[g]);
      accL2[g] = MFMA16(e3, B2[g][3], accL2[g]);
      accL2[g] = MFMA16(e4, B2[g][4], accL2[g]);
      accL2[g] = MFMA16(e5, B2[g][5], accL2[g]);
    }
    #pragma unroll
    for (int s = 0; s < 2; ++s) {
      float g0 = (w < 4) ? accL2[0][s] : accL2[0][2 + s];
      float g1 = (w < 4) ? accL2[1][s] : accL2[1][2 + s];
      float g2 = (w < 4) ? accL2[2][s] : accL2[2][2 + s];
      float g3 = (w < 4) ? accL2[3][s] : accL2[3][2 + s];
      float ii = sigf(g0 + bi2[0]), ff = sigf(g1 + bi2[1]);
      float gg = tanhf_(g2 + bi2[2]), oo = sigf(g3 + bi2[3]);
      c2[s] = fmaf(ff, c2[s], ii * gg);
      float h2v = oo * tanhf_(c2[s]);
      if (q < 2) {
        *(_Float16*)(pW + (h2base + s * 384 + (sk ^ ((s & 1) << 6)))) = (_Float16)h2v;
        if (t == TS - 1) h2f[4 * q + regbase + s][u2] = h2v;
      }
    }
  }

  // ---- dense head (fp32) ----
  __syncthreads();
  if (tid < 200) {
    int r = tid / 25, d = tid - r * 25;
    float acc = b_d1[d];
    #pragma unroll
    for (int uu = 0; uu < 64; ++uu) acc = fmaf(h2f[r][uu], w_d1[d * 64 + uu], acc);
    dh[tid] = acc;
  }
  __syncthreads();
  if (tid < 8) {
    float y = b_d2[0];
    #pragma unroll
    for (int d = 0; d < 25; ++d) y = fmaf(dh[tid * 25 + d], w_d2[d], y);
    out[r0 + tid] = y;
  }
}

extern "C" void kernel_launch(void* const* d_in, const int* in_sizes, int n_in,
                              void* d_out, int out_size, void* d_ws, size_t ws_size,
                              hipStream_t stream) {
  (void)in_sizes; (void)n_in; (void)out_size; (void)ws_size;
  const float* x     = (const float*)d_in[0];
  const float* w_ih1 = (const float*)d_in[1];
  const float* w_hh1 = (const float*)d_in[2];
  const float* b_ih1 = (const float*)d_in[3];
  const float* b_hh1 = (const float*)d_in[4];
  const float* w_ih2 = (const float*)d_in[5];
  const float* w_hh2 = (const float*)d_in[6];
  const float* b_ih2 = (const float*)d_in[7];
  const float* b_hh2 = (const float*)d_in[8];
  const float* w_d1  = (const float*)d_in[9];
  const float* b_d1  = (const float*)d_in[10];
  const float* w_d2  = (const float*)d_in[11];
  const float* b_d2  = (const float*)d_in[12];
  _Float16* wsh = (_Float16*)d_ws;
  float* outp = (float*)d_out;

  prep<<<320, 512, 0, stream>>>(w_hh1, w_ih2, w_hh2, wsh);
  lstm_mfma<<<256, 512, 0, stream>>>(x, w_ih1, b_ih1, b_hh1, b_ih2, b_hh2,
                                     w_d1, b_d1, w_d2, b_d2, wsh, outp);
}